// Round 5
// baseline (126.901 us; speedup 1.0000x reference)
//
#include <hip/hip_runtime.h>

// OPU via MFMA. R20 = R17 presplit (unchanged) + main: 64x32 tiles, grid 1024 =
// 4 blocks/CU -> 4 waves/SIMD, k-split 4 waves x 16 chunks, LDS-atomic combine.
// R19 post-mortem (90.6, +4.7): 8-wave kh x quadrant split doubled block VMEM
// (1024 b128 vs 512; L1 didn't absorb the half-page duplication) -> traffic, not
// occupancy, was the delta. Lesson: raise TLP only at UNCHANGED block-load totals.
// R20: 256-thr blocks keep R17's zero-duplication k-split; tile 64x32 halves per-block
// work so grid 1024 = exactly 4 blocks/CU (one pass, no tail). Per wave: 16 chunks x
// 6 b128 (full A page + owned B half-page), res[2][16]=32 VGPR, ~100 total < 128 cap
// (launch_bounds(256,4)). Per-SIMD: MFMA 3072cyc / quant 4096cyc identical to R17,
// VMEM 1024->1536cyc, in-flight loads 16->24, waves 2->4. Grid traffic 256->384MB
// (A read x32) at ~15TB/s << 34.5TB/s L2 ceiling. Combine: cb zero + ds_add_f32
// atomics (exact: integer-valued f32, order-independent), 2 barriers vs 4 serial.
// Swizzle: per-XCD 8-mblk x 16-nblk region = A 2MB + B 2MB (R17's L2 budget).
// Carried: biased-magic quant (res at 1.5*2^23; fp32 RNE in res+=acc IS the per-chunk
// ADC rint; swing <=1120 << 4.19M), table-driven presplit (bit-identical), W folded
// into 512 X-blocks, merged-plane 4KB pages, AlBl dropped (|err|<=4e-6), clip dead.
// R16 lesson: hipLaunchCooperativeKernel never executes under graph capture -> banned.

typedef unsigned int u32;
typedef unsigned short u16;
typedef _Float16 f16x8 __attribute__((ext_vector_type(8)));
typedef float f32x16 __attribute__((ext_vector_type(16)));

#define M_TOT 2048
#define N_TOT 1024
#define K_TOT 1024
#define RBIAS 12582912.0f  // 1.5 * 2^23: fp32 ulp = 1.0, integer-grid RNE in the add

__device__ __forceinline__ u32 split_pack(float a) {
  _Float16 h = (_Float16)a;              // v_cvt_f16_f32 (RNE)
  _Float16 l = (_Float16)(a - (float)h); // exact fp32 sub then RNE
  return (u32)__builtin_bit_cast(u16, h) | ((u32)__builtin_bit_cast(u16, l) << 16);
}
__device__ __forceinline__ u32 pk_lo(u32 a, u32 b) { return (a & 0xffffu) | (b << 16); }
__device__ __forceinline__ u32 pk_hi(u32 a, u32 b) { return (a >> 16) | (b & 0xffff0000u); }

__global__ __launch_bounds__(256) void presplit(
    const float* __restrict__ x, const float* __restrict__ w,
    const float* __restrict__ vl, const float* __restrict__ wl,
    u16* __restrict__ XHL, u16* __restrict__ WHL)
{
  __shared__ __align__(16) char lds[16384];  // X 4-chunk plane image
  __shared__ u32 tabX[256];
  __shared__ u32 tabW[256];

  const int b   = blockIdx.x;   // 512 blocks: each does one X tile-group AND one W slice
  const int tid = threadIdx.x;

  // ---- split tables: a = fl(x + vlut) (X) and fl(fl(w + wlut) * 1/16) (W) ----
  {
    const int j = tid >> 4, xi = tid & 15;
    const float base = (float)(xi - 8);
    tabX[tid] = split_pack(base + vl[j * 16 + xi]);
    tabW[tid] = split_pack((base + wl[j * 16 + xi]) * 0.0625f);
  }
  __syncthreads();

  // ---- W presplit: thread = one (ch, oct, n) item; 512*256 == 128*1024 exactly ----
  {
    const int g2 = b * 256 + tid;
    const int n  = g2 & 1023;
    const int co = g2 >> 10;                // 0..127 = (ch, oct)
    const int ch = co >> 1, oct = co & 1;
    const int nblk = n >> 6, ng = (n >> 5) & 1, n32 = n & 31;
    const float* wp = w + (size_t)(ch * 16 + oct * 8) * N_TOT + n;

    u32 hp[4], lp[4];
#pragma unroll
    for (int e2 = 0; e2 < 4; ++e2) {
      const int e = e2 * 2;
      const float w0 = wp[(size_t)e * N_TOT];
      const float w1 = wp[(size_t)(e + 1) * N_TOT];
      const u32 t0 = tabW[(oct * 8 + e) * 16 + (int)(w0 + 8.0f)];
      const u32 t1 = tabW[(oct * 8 + e + 1) * 16 + (int)(w1 + 8.0f)];
      hp[e2] = pk_lo(t0, t1);
      lp[e2] = pk_hi(t0, t1);
    }
    // chunk base (u16): (nblk*64+ch)*2048 ; layout hl*1024 + ng*512 + oct*256 + n32*8
    const size_t wb = (size_t)(nblk * 64 + ch) * 2048 + ng * 512 + oct * 256 + n32 * 8;
    *(uint4*)&WHL[wb]        = make_uint4(hp[0], hp[1], hp[2], hp[3]);
    *(uint4*)&WHL[wb + 1024] = make_uint4(lp[0], lp[1], lp[2], lp[3]);
  }

  // ---- X presplit: block = (mblk, chunk-group of 4) ----
  {
    const int mblk = b >> 4, chg = b & 15;
    const int ml = tid >> 2, chl = tid & 3;
    const int rg = ml >> 5, row = ml & 31;
    const float4* xp4 = (const float4*)(x + (size_t)(mblk * 64 + ml) * K_TOT + (chg * 4 + chl) * 16);
    float4 v4[4] = { xp4[0], xp4[1], xp4[2], xp4[3] };
    const float* v = (const float*)v4;

    u32 hp[8], lp[8];
#pragma unroll
    for (int e2 = 0; e2 < 8; ++e2) {
      const int e = e2 * 2;
      const u32 t0 = tabX[e * 16 + (int)(v[e] + 8.0f)];
      const u32 t1 = tabX[(e + 1) * 16 + (int)(v[e + 1] + 8.0f)];
      hp[e2] = pk_lo(t0, t1);
      lp[e2] = pk_hi(t0, t1);
    }

    // LDS image in exact global layout: chl*4096 + hl*2048 + rg*1024 + oct*512 + row*16
    char* basep = lds + chl * 4096 + rg * 1024 + row * 16;
    *(uint4*)(basep)        = make_uint4(hp[0], hp[1], hp[2], hp[3]);  // h oct0
    *(uint4*)(basep + 512)  = make_uint4(hp[4], hp[5], hp[6], hp[7]);  // h oct1
    *(uint4*)(basep + 2048) = make_uint4(lp[0], lp[1], lp[2], lp[3]);  // l oct0
    *(uint4*)(basep + 2560) = make_uint4(lp[4], lp[5], lp[6], lp[7]);  // l oct1
    __syncthreads();

    // coalesced dump: 16KB contiguous (4 chunk-planes)
    const size_t gb = (size_t)(mblk * 64 + chg * 4) * 4096;  // bytes
    const int off = tid * 16;
    *(uint4*)((char*)XHL + gb + off)         = *(const uint4*)(lds + off);
    *(uint4*)((char*)XHL + gb + off + 4096)  = *(const uint4*)(lds + off + 4096);
    *(uint4*)((char*)XHL + gb + off + 8192)  = *(const uint4*)(lds + off + 8192);
    *(uint4*)((char*)XHL + gb + off + 12288) = *(const uint4*)(lds + off + 12288);
  }
}

__global__ __launch_bounds__(256, 4) void opu_main(
    const u16* __restrict__ XHL, const u16* __restrict__ WHL,
    float* __restrict__ out)
{
  __shared__ float cb[64 * 32];   // 8KB combine buffer (64 rows x 32 cols)

  const int tid  = threadIdx.x;
  const int wave = tid >> 6;      // k-slice: chunks [wave*16, wave*16+16)
  const int lane = tid & 63;
  const int oct  = lane >> 5;
  const int ll   = lane & 31;

  // swizzle: xcd = bx&7 owns a contiguous 8-mblk x 16-nblk region (A 2MB + B 2MB L2 set)
  const int bx   = blockIdx.x;          // 0..1023
  const int xcd  = bx & 7;
  const int i7   = bx >> 3;             // 0..127
  const int mblk = (xcd >> 1) * 8 + (i7 >> 4);   // 0..31
  const int nblk = (xcd & 1) * 16 + (i7 & 15);   // 0..31 (32-col tiles)

  // A: full 4KB chunk pages of mblk; B: owned ng half (512 u16) of nblk>>1 pages.
  const u16* pA = XHL + (size_t)mblk * 131072 + (size_t)(wave * 16) * 2048 + lane * 8;
  const u16* pB = WHL + (size_t)(nblk >> 1) * 131072 + (size_t)(wave * 16) * 2048
                      + (nblk & 1) * 512 + lane * 8;

  uint4 c0[6], c1[6];  // literal-indexed only (R7 lesson: ring idx -> scratch)

#define LQ(dst, ch)                                        \
  do {                                                     \
    const size_t o = (size_t)(ch) * 2048;                  \
    (dst)[0] = *(const uint4*)(pA + o);                    \
    (dst)[1] = *(const uint4*)(pA + o + 512);              \
    (dst)[2] = *(const uint4*)(pA + o + 1024);             \
    (dst)[3] = *(const uint4*)(pA + o + 1536);             \
    (dst)[4] = *(const uint4*)(pB + o);                    \
    (dst)[5] = *(const uint4*)(pB + o + 1024);             \
  } while (0)

  float res[2][16];
#pragma unroll
  for (int t = 0; t < 2; ++t)
#pragma unroll
    for (int i = 0; i < 16; ++i) res[t][i] = RBIAS;  // biased: add RNE-rounds to int grid
  const f32x16 fzero = {};

  // Per chunk: two independent 3-MFMA chains (rg0, rg1); biased res += acc = ADC rint.
#define CQ(c)                                                                     \
  do {                                                                            \
    const f16x8 Ah0 = __builtin_bit_cast(f16x8, (c)[0]);                          \
    const f16x8 Ah1 = __builtin_bit_cast(f16x8, (c)[1]);                          \
    const f16x8 Al0 = __builtin_bit_cast(f16x8, (c)[2]);                          \
    const f16x8 Al1 = __builtin_bit_cast(f16x8, (c)[3]);                          \
    const f16x8 Bh  = __builtin_bit_cast(f16x8, (c)[4]);                          \
    const f16x8 Bl  = __builtin_bit_cast(f16x8, (c)[5]);                          \
    f32x16 a0 = __builtin_amdgcn_mfma_f32_32x32x16_f16(Ah0, Bh, fzero, 0, 0, 0);  \
    f32x16 a1 = __builtin_amdgcn_mfma_f32_32x32x16_f16(Ah1, Bh, fzero, 0, 0, 0);  \
    a0 = __builtin_amdgcn_mfma_f32_32x32x16_f16(Al0, Bh, a0, 0, 0, 0);            \
    a1 = __builtin_amdgcn_mfma_f32_32x32x16_f16(Al1, Bh, a1, 0, 0, 0);            \
    a0 = __builtin_amdgcn_mfma_f32_32x32x16_f16(Ah0, Bl, a0, 0, 0, 0);            \
    a1 = __builtin_amdgcn_mfma_f32_32x32x16_f16(Ah1, Bl, a1, 0, 0, 0);            \
    _Pragma("unroll")                                                             \
    for (int i = 0; i < 16; ++i) res[0][i] += a0[i];                              \
    _Pragma("unroll")                                                             \
    for (int i = 0; i < 16; ++i) res[1][i] += a1[i];                              \
  } while (0)

  // zero the combine buffer while first loads are in flight
  LQ(c0, 0);
  {
    float4* cbz = (float4*)cb;
    cbz[tid * 2]     = make_float4(0.f, 0.f, 0.f, 0.f);
    cbz[tid * 2 + 1] = make_float4(0.f, 0.f, 0.f, 0.f);
  }

#pragma unroll 1
  for (int it = 0; it < 8; ++it) {
    LQ(c1, 2 * it + 1);
    CQ(c0);
    if (it < 7) LQ(c0, 2 * it + 2);
    CQ(c1);
  }

  // ---- combine via LDS float atomics (exact: integer-valued f32, order-free) ----
  __syncthreads();   // cb zeroed by all, loads done
#pragma unroll
  for (int rg = 0; rg < 2; ++rg)
#pragma unroll
    for (int i = 0; i < 16; ++i) {
      const int r = (i & 3) + 8 * (i >> 2) + 4 * oct;
      atomicAdd(&cb[(rg * 32 + r) * 32 + ll], res[rg][i] - RBIAS);
    }
  __syncthreads();

  // ---- cooperative store: 256 threads x 8 floats ----
  const float4* cbv = (const float4*)cb;
  const int row = tid >> 2, c4 = tid & 3;
  float* orow = out + (size_t)(mblk * 64 + row) * N_TOT + nblk * 32;
#pragma unroll
  for (int p = 0; p < 2; ++p) {
    float4 v = cbv[row * 8 + c4 * 2 + p];
    v.x *= 16.0f; v.y *= 16.0f; v.z *= 16.0f; v.w *= 16.0f;
    *(float4*)&orow[(c4 * 2 + p) * 4] = v;
  }
}

extern "C" void kernel_launch(void* const* d_in, const int* in_sizes, int n_in,
                              void* d_out, int out_size, void* d_ws, size_t ws_size,
                              hipStream_t stream)
{
  const float* input  = (const float*)d_in[0];
  const float* weight = (const float*)d_in[1];
  const float* vmap   = (const float*)d_in[2];
  const float* wmap   = (const float*)d_in[3];
  float* out = (float*)d_out;

  u16* XHL = (u16*)d_ws;                         // 8MB (4M u16)
  u16* WHL = XHL + 4 * 1024 * 1024;              // 4MB   (ws use: 12MB total)

  presplit<<<512, 256, 0, stream>>>(input, weight, vmap, wmap, XHL, WHL);

  opu_main<<<1024, 256, 0, stream>>>(XHL, WHL, out);
}

// Round 6
// 87.906 us; speedup vs baseline: 1.4436x; 1.4436x over previous
//
#include <hip/hip_runtime.h>

// OPU via MFMA. R21 = R17 EXACT structure (presplit unchanged, main 64x64 k-split,
// 256thr/2-blocks-per-CU) + two surgical main changes: depth-3 prefetch (4-buffer
// literal rotation) and half-chunk COMPUTE split with f32x2 (v_pk_add_f32) quant.
// R20 post-mortem (126.9; main visible at 59.9us): MfmaUtil 8%, VALUBusy 5%, VGPR=60
// << the ~110 needed -> (256,4) reg-cap made the compiler sink loads to uses, zero
// lookahead, full L2 latency per chunk. Occupancy-via-restructure now falsified 3x
// (R18 +9, R19 +4.7, R20 +41). Lesson: keep R17's 2-wave/SIMD shape (cap 256 regs,
// only ~112 used) and buy latency cover with VGPRs, not waves.
// R17 main accounting: per-SIMD MFMA 12.3Kcyc, quant 16.4Kcyc (overlap -> 6.8us floor)
// + ~32 load->compute round trips at 1-chunk lookahead (~450cyc cover vs 300-500cyc
// L2 latency) = ~24us observed. R21: (1) 4 chunk-buffers, 3-deep prefetch, 24 b128 in
// flight (~1350cyc cover), +64 VGPR -> ~210 < 256 cap; (2) COMPUTE split into a0,a1
// then a2,a3 halves live accs 64->32 regs, quant as f32x2 += (pk-add candidate,
// halves quant VALU if packed; bit-identical RNE fp32 per lane).
// Carried: biased-magic quant (res at 1.5*2^23; fp32 RNE in res+=acc IS the per-chunk
// ADC rint; swing <=1120 << 4.19M margin), merged-plane 4KB/chunk pages, table-driven
// presplit (bit-identical), W folded into 512 X-blocks, AlBl dropped (|err|<=4e-6),
// clip provably dead, 4-step wave-serial combine, x16 store, per-XCD swizzle.
// R16 lesson: hipLaunchCooperativeKernel never executes under graph capture -> banned.

typedef unsigned int u32;
typedef unsigned short u16;
typedef _Float16 f16x8 __attribute__((ext_vector_type(8)));
typedef float f32x16 __attribute__((ext_vector_type(16)));
typedef float f32x2  __attribute__((ext_vector_type(2)));

#define M_TOT 2048
#define N_TOT 1024
#define K_TOT 1024
#define RBIAS 12582912.0f  // 1.5 * 2^23: fp32 ulp = 1.0, integer-grid RNE in the add

__device__ __forceinline__ u32 split_pack(float a) {
  _Float16 h = (_Float16)a;              // v_cvt_f16_f32 (RNE)
  _Float16 l = (_Float16)(a - (float)h); // exact fp32 sub then RNE
  return (u32)__builtin_bit_cast(u16, h) | ((u32)__builtin_bit_cast(u16, l) << 16);
}
__device__ __forceinline__ u32 pk_lo(u32 a, u32 b) { return (a & 0xffffu) | (b << 16); }
__device__ __forceinline__ u32 pk_hi(u32 a, u32 b) { return (a >> 16) | (b & 0xffff0000u); }

__global__ __launch_bounds__(256) void presplit(
    const float* __restrict__ x, const float* __restrict__ w,
    const float* __restrict__ vl, const float* __restrict__ wl,
    u16* __restrict__ XHL, u16* __restrict__ WHL)
{
  __shared__ __align__(16) char lds[16384];  // X 4-chunk plane image
  __shared__ u32 tabX[256];
  __shared__ u32 tabW[256];

  const int b   = blockIdx.x;   // 512 blocks: each does one X tile-group AND one W slice
  const int tid = threadIdx.x;

  // ---- split tables: a = fl(x + vlut) (X) and fl(fl(w + wlut) * 1/16) (W) ----
  {
    const int j = tid >> 4, xi = tid & 15;
    const float base = (float)(xi - 8);
    tabX[tid] = split_pack(base + vl[j * 16 + xi]);
    tabW[tid] = split_pack((base + wl[j * 16 + xi]) * 0.0625f);
  }
  __syncthreads();

  // ---- W presplit: thread = one (ch, oct, n) item; 512*256 == 128*1024 exactly ----
  {
    const int g2 = b * 256 + tid;
    const int n  = g2 & 1023;
    const int co = g2 >> 10;                // 0..127 = (ch, oct)
    const int ch = co >> 1, oct = co & 1;
    const int nblk = n >> 6, ng = (n >> 5) & 1, n32 = n & 31;
    const float* wp = w + (size_t)(ch * 16 + oct * 8) * N_TOT + n;

    u32 hp[4], lp[4];
#pragma unroll
    for (int e2 = 0; e2 < 4; ++e2) {
      const int e = e2 * 2;
      const float w0 = wp[(size_t)e * N_TOT];
      const float w1 = wp[(size_t)(e + 1) * N_TOT];
      const u32 t0 = tabW[(oct * 8 + e) * 16 + (int)(w0 + 8.0f)];
      const u32 t1 = tabW[(oct * 8 + e + 1) * 16 + (int)(w1 + 8.0f)];
      hp[e2] = pk_lo(t0, t1);
      lp[e2] = pk_hi(t0, t1);
    }
    // chunk base (u16): (nblk*64+ch)*2048 ; layout hl*1024 + ng*512 + oct*256 + n32*8
    const size_t wb = (size_t)(nblk * 64 + ch) * 2048 + ng * 512 + oct * 256 + n32 * 8;
    *(uint4*)&WHL[wb]        = make_uint4(hp[0], hp[1], hp[2], hp[3]);
    *(uint4*)&WHL[wb + 1024] = make_uint4(lp[0], lp[1], lp[2], lp[3]);
  }

  // ---- X presplit: block = (mblk, chunk-group of 4) ----
  {
    const int mblk = b >> 4, chg = b & 15;
    const int ml = tid >> 2, chl = tid & 3;
    const int rg = ml >> 5, row = ml & 31;
    const float4* xp4 = (const float4*)(x + (size_t)(mblk * 64 + ml) * K_TOT + (chg * 4 + chl) * 16);
    float4 v4[4] = { xp4[0], xp4[1], xp4[2], xp4[3] };
    const float* v = (const float*)v4;

    u32 hp[8], lp[8];
#pragma unroll
    for (int e2 = 0; e2 < 8; ++e2) {
      const int e = e2 * 2;
      const u32 t0 = tabX[e * 16 + (int)(v[e] + 8.0f)];
      const u32 t1 = tabX[(e + 1) * 16 + (int)(v[e + 1] + 8.0f)];
      hp[e2] = pk_lo(t0, t1);
      lp[e2] = pk_hi(t0, t1);
    }

    // LDS image in exact global layout: chl*4096 + hl*2048 + rg*1024 + oct*512 + row*16
    char* basep = lds + chl * 4096 + rg * 1024 + row * 16;
    *(uint4*)(basep)        = make_uint4(hp[0], hp[1], hp[2], hp[3]);  // h oct0
    *(uint4*)(basep + 512)  = make_uint4(hp[4], hp[5], hp[6], hp[7]);  // h oct1
    *(uint4*)(basep + 2048) = make_uint4(lp[0], lp[1], lp[2], lp[3]);  // l oct0
    *(uint4*)(basep + 2560) = make_uint4(lp[4], lp[5], lp[6], lp[7]);  // l oct1
    __syncthreads();

    // coalesced dump: 16KB contiguous (4 chunk-planes)
    const size_t gb = (size_t)(mblk * 64 + chg * 4) * 4096;  // bytes
    const int off = tid * 16;
    *(uint4*)((char*)XHL + gb + off)         = *(const uint4*)(lds + off);
    *(uint4*)((char*)XHL + gb + off + 4096)  = *(const uint4*)(lds + off + 4096);
    *(uint4*)((char*)XHL + gb + off + 8192)  = *(const uint4*)(lds + off + 8192);
    *(uint4*)((char*)XHL + gb + off + 12288) = *(const uint4*)(lds + off + 12288);
  }
}

__global__ __launch_bounds__(256, 2) void opu_main(
    const u16* __restrict__ XHL, const u16* __restrict__ WHL,
    float* __restrict__ out)
{
  __shared__ float cb[64 * 64];   // 16KB combine buffer

  const int tid  = threadIdx.x;
  const int wave = tid >> 6;      // k-slice: chunks [wave*16, wave*16+16)
  const int lane = tid & 63;
  const int oct  = lane >> 5;
  const int ll   = lane & 31;

  const int bx   = blockIdx.x;
  const int nblk = (bx & 1) + 2 * ((bx >> 3) & 7);   // 0..15
  const int mblk = ((bx >> 1) & 3) + 4 * (bx >> 6);  // 0..31

  // chunk stride 2048 u16 (4KB page: [hl][rg|ng][oct][32][k8])
  const u16* pA = XHL + (size_t)mblk * 131072 + (size_t)(wave * 16) * 2048 + lane * 8;
  const u16* pB = WHL + (size_t)nblk * 131072 + (size_t)(wave * 16) * 2048 + lane * 8;

  uint4 q0[8], q1[8], q2[8], q3[8];  // literal-indexed only (R7 lesson: ring idx -> scratch)

#define LOADCH(dst, ch)                                   \
  do {                                                    \
    const size_t o = (size_t)(ch) * 2048;                 \
    (dst)[0] = *(const uint4*)(pA + o);                   \
    (dst)[1] = *(const uint4*)(pA + o + 512);             \
    (dst)[2] = *(const uint4*)(pA + o + 1024);            \
    (dst)[3] = *(const uint4*)(pA + o + 1536);            \
    (dst)[4] = *(const uint4*)(pB + o);                   \
    (dst)[5] = *(const uint4*)(pB + o + 512);             \
    (dst)[6] = *(const uint4*)(pB + o + 1024);            \
    (dst)[7] = *(const uint4*)(pB + o + 1536);            \
  } while (0)

  f32x2 res[4][8];
#pragma unroll
  for (int t = 0; t < 4; ++t)
#pragma unroll
    for (int i = 0; i < 8; ++i) { res[t][i].x = RBIAS; res[t][i].y = RBIAS; }
  const f32x16 fzero = {};

  // Half-chunk compute: 2 live accs at a time (32 regs not 64); biased f32x2 += acc
  // performs the per-chunk ADC rint (pk-add candidate, per-lane IEEE RNE identical).
#define CHALF(Ahx, Alx, c, r0, r1)                                                 \
  do {                                                                             \
    const f16x8 Ah = __builtin_bit_cast(f16x8, (c)[Ahx]);                          \
    const f16x8 Al = __builtin_bit_cast(f16x8, (c)[Alx]);                          \
    const f16x8 Bh0 = __builtin_bit_cast(f16x8, (c)[4]);                           \
    const f16x8 Bh1 = __builtin_bit_cast(f16x8, (c)[5]);                           \
    const f16x8 Bl0 = __builtin_bit_cast(f16x8, (c)[6]);                           \
    const f16x8 Bl1 = __builtin_bit_cast(f16x8, (c)[7]);                           \
    f32x16 a0 = __builtin_amdgcn_mfma_f32_32x32x16_f16(Ah, Bh0, fzero, 0, 0, 0);   \
    f32x16 a1 = __builtin_amdgcn_mfma_f32_32x32x16_f16(Ah, Bh1, fzero, 0, 0, 0);   \
    a0 = __builtin_amdgcn_mfma_f32_32x32x16_f16(Al, Bh0, a0, 0, 0, 0);             \
    a1 = __builtin_amdgcn_mfma_f32_32x32x16_f16(Al, Bh1, a1, 0, 0, 0);             \
    a0 = __builtin_amdgcn_mfma_f32_32x32x16_f16(Ah, Bl0, a0, 0, 0, 0);             \
    a1 = __builtin_amdgcn_mfma_f32_32x32x16_f16(Ah, Bl1, a1, 0, 0, 0);             \
    _Pragma("unroll")                                                              \
    for (int i = 0; i < 8; ++i) {                                                  \
      f32x2 t0; t0.x = a0[2 * i]; t0.y = a0[2 * i + 1];                            \
      f32x2 t1; t1.x = a1[2 * i]; t1.y = a1[2 * i + 1];                            \
      res[r0][i] += t0;                                                            \
      res[r1][i] += t1;                                                            \
    }                                                                              \
  } while (0)

#define COMPUTE(c)                \
  do {                            \
    CHALF(0, 2, c, 0, 1);         \
    CHALF(1, 3, c, 2, 3);         \
  } while (0)

#define CL15(v) ((v) > 15 ? 15 : (v))

  // Depth-3 prefetch over this wave's 16 chunks (wave base already in pA/pB).
  LOADCH(q0, 0); LOADCH(q1, 1); LOADCH(q2, 2);
#pragma unroll 1
  for (int it = 0; it < 4; ++it) {
    const int ch = it * 4;
    LOADCH(q3, ch + 3);          COMPUTE(q0);
    LOADCH(q0, CL15(ch + 4));    COMPUTE(q1);   // tail prefetches redundantly reload 15
    LOADCH(q1, CL15(ch + 5));    COMPUTE(q2);
    LOADCH(q2, CL15(ch + 6));    COMPUTE(q3);
  }

  // ---- combine the 4 waves' k-slices through LDS (subtract bias -> exact ints) ----
#define CBIDX(mt, nt, i) ((((mt) * 32) + ((i & 3) + 8 * (i >> 2) + 4 * oct)) * 64 + (nt) * 32 + ll)
  if (wave == 0) {
#pragma unroll
    for (int mt = 0; mt < 2; ++mt)
#pragma unroll
      for (int nt = 0; nt < 2; ++nt) {
        const float* rt = (const float*)&res[mt * 2 + nt][0];
#pragma unroll
        for (int i = 0; i < 16; ++i) cb[CBIDX(mt, nt, i)] = rt[i] - RBIAS;
      }
  }
  __syncthreads();
  if (wave == 1) {
#pragma unroll
    for (int mt = 0; mt < 2; ++mt)
#pragma unroll
      for (int nt = 0; nt < 2; ++nt) {
        const float* rt = (const float*)&res[mt * 2 + nt][0];
#pragma unroll
        for (int i = 0; i < 16; ++i) cb[CBIDX(mt, nt, i)] += rt[i] - RBIAS;
      }
  }
  __syncthreads();
  if (wave == 2) {
#pragma unroll
    for (int mt = 0; mt < 2; ++mt)
#pragma unroll
      for (int nt = 0; nt < 2; ++nt) {
        const float* rt = (const float*)&res[mt * 2 + nt][0];
#pragma unroll
        for (int i = 0; i < 16; ++i) cb[CBIDX(mt, nt, i)] += rt[i] - RBIAS;
      }
  }
  __syncthreads();
  if (wave == 3) {
#pragma unroll
    for (int mt = 0; mt < 2; ++mt)
#pragma unroll
      for (int nt = 0; nt < 2; ++nt) {
        const float* rt = (const float*)&res[mt * 2 + nt][0];
#pragma unroll
        for (int i = 0; i < 16; ++i) cb[CBIDX(mt, nt, i)] += rt[i] - RBIAS;
      }
  }
  __syncthreads();

  // ---- cooperative x16 store ----
  const float4* cbv = (const float4*)cb;
  const int row = tid >> 2, c4 = tid & 3;
  float* orow = out + (size_t)(mblk * 64 + row) * N_TOT + nblk * 64;
#pragma unroll
  for (int p = 0; p < 4; ++p) {
    float4 v = cbv[row * 16 + c4 + 4 * p];
    v.x *= 16.0f; v.y *= 16.0f; v.z *= 16.0f; v.w *= 16.0f;
    *(float4*)&orow[(c4 + 4 * p) * 4] = v;
  }
}

extern "C" void kernel_launch(void* const* d_in, const int* in_sizes, int n_in,
                              void* d_out, int out_size, void* d_ws, size_t ws_size,
                              hipStream_t stream)
{
  const float* input  = (const float*)d_in[0];
  const float* weight = (const float*)d_in[1];
  const float* vmap   = (const float*)d_in[2];
  const float* wmap   = (const float*)d_in[3];
  float* out = (float*)d_out;

  u16* XHL = (u16*)d_ws;                         // 8MB (4M u16)
  u16* WHL = XHL + 4 * 1024 * 1024;              // 4MB   (ws use: 12MB total)

  presplit<<<512, 256, 0, stream>>>(input, weight, vmap, wmap, XHL, WHL);

  opu_main<<<512, 256, 0, stream>>>(XHL, WHL, out);
}